// Round 2
// baseline (1439.330 us; speedup 1.0000x reference)
//
#include <hip/hip_runtime.h>

// GRU: x(512,512) int32 tokens, emb(32000,128) f32, W_ih(768,128), W_hh(768,256),
// b_ih(768), b_hh(768). out = h_T (512,256) f32.
//
// Phase A: convert emb/W_ih/W_hh to bf16 in ws (8.78 MB).
// Phase B: gi[t] = W_ih @ emb[x[:,t]]^T + b_ih (+ b_hh for r/z), bf16, stored in a
//          ws ring of C timesteps in a *pre-swizzled* byte layout so the recurrence
//          can stage it with linear global_load_lds and read it conflict-free.
// Phase C: 32 blocks x 512 thr; block owns 16 batch rows, loops C steps.
//          W_hh register-resident (192 VGPR/lane), h via swizzled LDS.
// ws-size-adaptive chunking: h state crosses chunk boundaries via d_out (f32).

typedef unsigned short ushort_t;
typedef __attribute__((ext_vector_type(8))) short short8;
typedef __attribute__((ext_vector_type(4))) float float4_;
typedef __attribute__((ext_vector_type(4))) unsigned short ushort4_;

#define VOCAB 32000
#define EMB 128
#define HID 256
#define G3 768
#define BB 512
#define TT 512
#define SLOT 786432      // gi bytes per timestep: 512 b * 768 g * 2
#define BLK_BYTES 24576  // gi bytes per (t, 16-batch block): 16*768*2
#define WFIXED 8781824   // emb16 + Wih16 + Whh16

__device__ __forceinline__ float b2f(ushort_t u) {
  return __uint_as_float(((unsigned)u) << 16);
}
__device__ __forceinline__ ushort_t f2b(float f) {
  unsigned u = __float_as_uint(f);
  return (ushort_t)((u + 0x7FFFu + ((u >> 16) & 1u)) >> 16);
}
__device__ __forceinline__ short8 ld8(const ushort_t* p) { return *(const short8*)p; }
__device__ __forceinline__ void gld_lds16(const void* g, void* l) {
  __builtin_amdgcn_global_load_lds((const __attribute__((address_space(1))) void*)g,
                                   (__attribute__((address_space(3))) void*)l, 16, 0, 0);
}
// swizzled byte offset of (b_local, gate g) inside a 24576-B (t,blk) tile
__device__ __forceinline__ int gi_byte(int bl, int twog) {
  return ((bl * 1536) + twog) ^ ((bl & 7) << 4);
}

// ---------------- Phase A: f32 -> bf16 ----------------
__global__ void cvt_bf16_k(const float* __restrict__ s, ushort_t* __restrict__ d, int n4) {
  int i = blockIdx.x * blockDim.x + threadIdx.x;
  int stride = gridDim.x * blockDim.x;
  for (; i < n4; i += stride) {
    float4_ v = ((const float4_*)s)[i];
    ushort4_ o;
    o.x = f2b(v.x); o.y = f2b(v.y); o.z = f2b(v.z); o.w = f2b(v.w);
    ((ushort4_*)d)[i] = o;
  }
}

// ---------------- Phase B: gi GEMM for t in [t0, t0+C) ----------------
// grid 2*C blocks x 256 thr; wave handles 4 n-tiles (64 (t,b) pairs), 48 m-tiles.
__global__ __launch_bounds__(256) void gi_gemm(
    const int* __restrict__ x, const ushort_t* __restrict__ emb16,
    const ushort_t* __restrict__ Wih16, const float* __restrict__ bih,
    const float* __restrict__ bhh, char* __restrict__ gic, int t0) {
  __shared__ float cb[G3];
  const int tid = threadIdx.x;
  for (int i = tid; i < G3; i += 256) cb[i] = bih[i] + (i < 512 ? bhh[i] : 0.f);
  __syncthreads();
  const int lane = tid & 63, w = tid >> 6;
  const int bl = lane & 15, kg = lane >> 4;
  const int nt0 = (blockIdx.x * 4 + w) * 4;

  short8 bfr[4][4];
#pragma unroll
  for (int j = 0; j < 4; ++j) {
    int nt = nt0 + j;
    int b = (nt & 31) * 16 + bl;
    int tok = x[b * TT + t0 + (nt >> 5)];
#pragma unroll
    for (int kt = 0; kt < 4; ++kt)
      bfr[j][kt] = ld8(emb16 + (size_t)tok * EMB + kt * 32 + kg * 8);
  }

#pragma unroll 1
  for (int mt = 0; mt < 48; ++mt) {
    short8 af[4];
#pragma unroll
    for (int kt = 0; kt < 4; ++kt)
      af[kt] = ld8(Wih16 + (mt * 16 + bl) * EMB + kt * 32 + kg * 8);
    float4_ z4 = {0.f, 0.f, 0.f, 0.f};
    float4_ acc[4] = {z4, z4, z4, z4};
#pragma unroll
    for (int kt = 0; kt < 4; ++kt) {
#pragma unroll
      for (int j = 0; j < 4; ++j)
        acc[j] = __builtin_amdgcn_mfma_f32_16x16x32_bf16(af[kt], bfr[j][kt], acc[j], 0, 0, 0);
    }
    int byte8 = gi_byte(bl, 32 * mt + 8 * kg);
#pragma unroll
    for (int j = 0; j < 4; ++j) {
      int nt = nt0 + j;
      size_t base = (size_t)(nt >> 5) * SLOT + (size_t)(nt & 31) * BLK_BYTES;
      ushort4_ o;
#pragma unroll
      for (int r = 0; r < 4; ++r)
        o[r] = f2b(acc[j][r] + cb[mt * 16 + kg * 4 + r]);
      *(ushort4_*)(gic + base + byte8) = o;
    }
  }
}

// ---------------- Phase C: recurrence for C steps ----------------
// 32 blocks x 512 thr (8 waves). Block owns batch rows [16*bx, +16).
// Wave w owns m-tiles {w+8i+16q}: per-wave-local r/z/n combine.
__global__ __launch_bounds__(512, 2) void gru_rec(
    const ushort_t* __restrict__ Whh16, const char* __restrict__ gic,
    const float* __restrict__ bhh, float* __restrict__ out, int t0, int C) {
  __shared__ alignas(16) ushort_t h_lds[2][16 * HID];  // [b][k], XOR-swizzled bytes
  __shared__ alignas(16) char gi_lds[2][BLK_BYTES];    // swizzled byte image of gi tile
  __shared__ float bhn_lds[HID];

  const int tid = threadIdx.x, lane = tid & 63, w = tid >> 6;
  const int bl = lane & 15, kg = lane >> 4;
  const int b0 = blockIdx.x * 16;
  const char* gblk = gic + (size_t)blockIdx.x * BLK_BYTES;

  // h_lds[0] init: zeros (t0==0) or bf16 of saved h (from out, f32 exact).
  if (t0 == 0) {
    for (int i = tid; i < 16 * HID; i += 512) h_lds[0][i] = 0;
  } else {
    for (int i = tid; i < 16 * HID; i += 512) {
      int b = i >> 8, k = i & 255;
      *(ushort_t*)((char*)h_lds[0] + (((b << 9) + 2 * k) ^ ((b & 7) << 4))) =
          f2b(out[(size_t)(b0 + b) * HID + k]);
    }
  }
  for (int i = tid; i < HID; i += 512) bhn_lds[i] = bhh[512 + i];

  // W_hh fragments, register-resident.
  short8 wf[2][3][8];
#pragma unroll
  for (int i = 0; i < 2; ++i) {
#pragma unroll
    for (int q = 0; q < 3; ++q) {
      int g = (w + 8 * i + 16 * q) * 16 + bl;
#pragma unroll
      for (int kt = 0; kt < 8; ++kt)
        wf[i][q][kt] = ld8(Whh16 + (size_t)g * HID + kt * 32 + kg * 8);
    }
  }

  float hreg[2][4];
#pragma unroll
  for (int i = 0; i < 2; ++i) {
    if (t0 == 0) {
#pragma unroll
      for (int r = 0; r < 4; ++r) hreg[i][r] = 0.f;
    } else {
      float4_ v = *(const float4_*)&out[(size_t)(b0 + bl) * HID + (w + 8 * i) * 16 + kg * 4];
#pragma unroll
      for (int r = 0; r < 4; ++r) hreg[i][r] = v[r];
    }
  }

  // prologue: stage gi slot 0 (linear 24576-B copy, swizzle baked into byte order)
  {
    int o = (w * 3) * 1024;
#pragma unroll
    for (int ii = 0; ii < 3; ++ii)
      gld_lds16(gblk + o + ii * 1024 + lane * 16, &gi_lds[0][o + ii * 1024]);
  }
  __syncthreads();

#pragma unroll 1
  for (int t = 0; t < C; ++t) {
    const int cur = t & 1, nxt = cur ^ 1;
    if (t + 1 < C) {
      const char* src = gblk + (size_t)(t + 1) * SLOT + (w * 3) * 1024;
#pragma unroll
      for (int ii = 0; ii < 3; ++ii)
        gld_lds16(src + ii * 1024 + lane * 16, &gi_lds[nxt][(w * 3) * 1024 + ii * 1024]);
    }

    // acc init: r/z from gi (biases prefolded), n from b_hh_n.
    float4_ acc[2][3];
#pragma unroll
    for (int i = 0; i < 2; ++i) {
#pragma unroll
      for (int q = 0; q < 2; ++q) {
        int byte8 = gi_byte(bl, 32 * (w + 8 * i + 16 * q) + 8 * kg);
        ushort4_ v = *(const ushort4_*)(&gi_lds[cur][byte8]);
#pragma unroll
        for (int r = 0; r < 4; ++r) acc[i][q][r] = b2f(v[r]);
      }
      acc[i][2] = *(const float4_*)&bhn_lds[(w + 8 * i) * 16 + kg * 4];
    }

    // gh += W_hh * h
#pragma unroll
    for (int kt = 0; kt < 8; ++kt) {
      int byteoff = ((bl * 512) + (kt * 32 + kg * 8) * 2) ^ ((bl & 7) << 4);
      short8 bf = *(const short8*)((const char*)h_lds[cur] + byteoff);
#pragma unroll
      for (int i = 0; i < 2; ++i) {
#pragma unroll
        for (int q = 0; q < 3; ++q)
          acc[i][q] = __builtin_amdgcn_mfma_f32_16x16x32_bf16(wf[i][q][kt], bf, acc[i][q], 0, 0, 0);
      }
    }

    // gates + h update, write h_{t+1} to other buffer.
#pragma unroll
    for (int i = 0; i < 2; ++i) {
      int byte8n = gi_byte(bl, 32 * (32 + w + 8 * i) + 8 * kg);
      ushort4_ gv = *(const ushort4_*)(&gi_lds[cur][byte8n]);
#pragma unroll
      for (int r = 0; r < 4; ++r) {
        float xr = acc[i][0][r];
        float xz = acc[i][1][r];
        float hn = acc[i][2][r];
        float rr = __builtin_amdgcn_rcpf(1.f + __expf(-xr));
        float zz = __builtin_amdgcn_rcpf(1.f + __expf(-xz));
        float y = b2f(gv[r]) + rr * hn;
        float nn = 1.f - 2.f * __builtin_amdgcn_rcpf(1.f + __expf(2.f * y));
        hreg[i][r] = (1.f - zz) * nn + zz * hreg[i][r];
      }
      int j0 = (w + 8 * i) * 16 + kg * 4;
      unsigned lo = (unsigned)f2b(hreg[i][0]) | ((unsigned)f2b(hreg[i][1]) << 16);
      unsigned hi = (unsigned)f2b(hreg[i][2]) | ((unsigned)f2b(hreg[i][3]) << 16);
      int byte0 = (bl * 512 + j0 * 2) ^ ((bl & 7) << 4);
      char* hp = (char*)h_lds[nxt];
      *(unsigned*)(hp + byte0) = lo;
      *(unsigned*)(hp + byte0 + 4) = hi;
    }
    __syncthreads();
  }

  // save h (f32) — final chunk leaves h_T in out.
#pragma unroll
  for (int i = 0; i < 2; ++i) {
    float4_ v = {hreg[i][0], hreg[i][1], hreg[i][2], hreg[i][3]};
    *(float4_*)&out[(size_t)(b0 + bl) * HID + (w + 8 * i) * 16 + kg * 4] = v;
  }
}

extern "C" void kernel_launch(void* const* d_in, const int* in_sizes, int n_in,
                              void* d_out, int out_size, void* d_ws, size_t ws_size,
                              hipStream_t stream) {
  const int* x = (const int*)d_in[0];
  const float* emb = (const float*)d_in[1];
  const float* Wih = (const float*)d_in[2];
  const float* Whh = (const float*)d_in[3];
  const float* bih = (const float*)d_in[4];
  const float* bhh = (const float*)d_in[5];
  float* out = (float*)d_out;

  char* ws = (char*)d_ws;
  ushort_t* emb16 = (ushort_t*)ws;                 // 8,192,000 B
  ushort_t* Wih16 = (ushort_t*)(ws + 8192000);     //   196,608 B
  ushort_t* Whh16 = (ushort_t*)(ws + 8388608);     //   393,216 B
  char* gic = ws + WFIXED;                         // gi ring, C slots

  // ws-adaptive chunk size
  size_t avail = ws_size > (size_t)WFIXED ? ws_size - (size_t)WFIXED : 0;
  int C = (int)(avail / (size_t)SLOT);
  if (C > TT) C = TT;
  if (C < 1) C = 1;

  cvt_bf16_k<<<1024, 256, 0, stream>>>(emb, emb16, (VOCAB * EMB) / 4);
  cvt_bf16_k<<<96, 256, 0, stream>>>(Wih, Wih16, (G3 * EMB) / 4);
  cvt_bf16_k<<<192, 256, 0, stream>>>(Whh, Whh16, (G3 * HID) / 4);

  for (int t0 = 0; t0 < TT; t0 += C) {
    int Cc = TT - t0 < C ? TT - t0 : C;
    gi_gemm<<<2 * Cc, 256, 0, stream>>>(x, emb16, Wih16, bih, bhh, gic, t0);
    gru_rec<<<32, 512, 0, stream>>>(Whh16, gic, bhh, out, t0, Cc);
  }
}